// Round 12
// baseline (409.211 us; speedup 1.0000x reference)
//
#include <hip/hip_runtime.h>
#include <hip/hip_fp16.h>

#define NN 50000
#define NE 800000
#define GB0 782       // gemm blocks in fused gemm0+hist1
#define NBLK1 391     // phase-1 blocks, 2048 edges each
#define NBUCK 196     // coarse buckets = dst>>8

typedef __attribute__((ext_vector_type(8))) short bf16x8;
typedef __attribute__((ext_vector_type(4))) float f32x4;
typedef __attribute__((ext_vector_type(2))) float f32x2;

__device__ inline float blo(unsigned u) { union { unsigned i; float f; } c; c.i = u << 16; return c.f; }
__device__ inline float bhi(unsigned u) { union { unsigned i; float f; } c; c.i = u & 0xFFFF0000u; return c.f; }
__device__ inline unsigned short f2b(float f) {
    union { float f; unsigned u; } c; c.f = f;
    return (unsigned short)((c.u + 0x7FFFu + ((c.u >> 16) & 1u)) >> 16);
}
__device__ inline unsigned pack2(float x, float y) {
    union { float f; unsigned u; } a, b; a.f = x; b.f = y;
    const unsigned lo = (a.u + 0x7FFFu + ((a.u >> 16) & 1u)) >> 16;
    const unsigned hi = (b.u + 0x7FFFu + ((b.u >> 16) & 1u)) & 0xFFFF0000u;
    return (lo & 0xFFFFu) | hi;
}
__device__ inline float edgew(unsigned u) {
    return __half2float(__ushort_as_half((unsigned short)(u >> 16)));
}
__device__ inline bf16x8 u4_to_b8(unsigned a, unsigned b, unsigned c, unsigned d) {
    union { unsigned u[4]; bf16x8 v; } x;
    x.u[0] = a; x.u[1] = b; x.u[2] = c; x.u[3] = d;
    return x.v;
}
// pack 4 fp32 -> 4 fp8 e4m3 (one uint)
__device__ inline unsigned pk_fp8x4(float a, float b, float c, float d) {
    int t = 0;
    t = __builtin_amdgcn_cvt_pk_fp8_f32(a, b, t, false);
    t = __builtin_amdgcn_cvt_pk_fp8_f32(c, d, t, true);
    return (unsigned)t;
}

// ================= weight packing =================
__device__ __forceinline__ void packb_body(const float* __restrict__ B, short* __restrict__ Bp, int NT, int b)
{
    const int o = b * 256 + threadIdx.x;
    if (o >= 4096 * NT) return;
    const int j = o & 7;
    const int lane = (o >> 3) & 63;
    const int tnt = o >> 9;
    const int nt = tnt % NT, ks = tnt / NT;
    const int k = ks * 32 + (lane >> 4) * 8 + j;
    const int n = nt * 16 + (lane & 15);
    Bp[o] = (short)f2b(B[k * (NT * 16) + n]);
}

__global__ __launch_bounds__(256) void packb0_k(const float* __restrict__ W0, short* __restrict__ Bp0)
{
    packb_body(W0, Bp0, 8, blockIdx.x);
}

// ================= MFMA GEMM body — LDS-free A-fragment loads =================
template <int NT, int MODE, bool FP8OUT>
__device__ __forceinline__ void gemm_body(
    const void* __restrict__ Av, const short* __restrict__ Bp,
    void* __restrict__ Cv, int M,
    const float* __restrict__ sum, const float* __restrict__ ss,
    const float* __restrict__ gam, const float* __restrict__ bet)
{
    constexpr int TC = (NT > 4) ? 4 : NT;
    constexpr int NCC = TC * 16;
    __shared__ float Cl[4][16 * NCC];
    __shared__ float scs[128], shs[128];
    const int tid = threadIdx.x;
    const int w = tid >> 6;
    const int lane = tid & 63;
    const int lane15 = lane & 15;
    const int quad = lane >> 4;
    const int row0 = blockIdx.x * 64;
    const int m = row0 + w * 16 + lane15;
    const int mc = (m < M) ? m : 0;

    if (MODE == 1) {
        if (tid < 128) {
            const float inv = 1.f / (float)M;
            const float mu = sum[tid] * inv;
            const float var = ss[tid] * inv - mu * mu;
            const float s = gam[tid] * rsqrtf(var + 1e-5f);
            scs[tid] = s;
            shs[tid] = bet[tid] - mu * s;
        }
        __syncthreads();
    }

    f32x4 acc[NT];
#pragma unroll
    for (int t = 0; t < NT; ++t) acc[t] = (f32x4){0.f, 0.f, 0.f, 0.f};

    if (MODE == 0) {
        const float* arow = (const float*)Av + (long)mc * 256;
#pragma unroll
        for (int ks = 0; ks < 8; ++ks) {
            const float4 v0 = *(const float4*)&arow[ks * 32 + quad * 8];
            const float4 v1 = *(const float4*)&arow[ks * 32 + quad * 8 + 4];
            const bf16x8 af = u4_to_b8(pack2(v0.x, v0.y), pack2(v0.z, v0.w),
                                       pack2(v1.x, v1.y), pack2(v1.z, v1.w));
#pragma unroll
            for (int t = 0; t < NT; ++t) {
                const bf16x8 bf = *(const bf16x8*)&Bp[(((ks * NT + t) * 64) + lane) * 8];
                acc[t] = __builtin_amdgcn_mfma_f32_16x16x32_bf16(af, bf, acc[t], 0, 0, 0);
            }
        }
    } else {
        const unsigned* arow = (const unsigned*)Av + (long)mc * 64;
#pragma unroll
        for (int ks = 0; ks < 4; ++ks) {
            const uint4 pv = *(const uint4*)&arow[ks * 16 + quad * 4];
            const bf16x8 apre = u4_to_b8(pv.x, pv.y, pv.z, pv.w);
            const int c0 = ks * 32 + quad * 8;
            const float4 s0 = *(const float4*)&scs[c0];
            const float4 s1 = *(const float4*)&scs[c0 + 4];
            const float4 h0 = *(const float4*)&shs[c0];
            const float4 h1 = *(const float4*)&shs[c0 + 4];
            const bf16x8 aact = u4_to_b8(
                pack2(fmaxf(fmaf(blo(pv.x), s0.x, h0.x), 0.f), fmaxf(fmaf(bhi(pv.x), s0.y, h0.y), 0.f)),
                pack2(fmaxf(fmaf(blo(pv.y), s0.z, h0.z), 0.f), fmaxf(fmaf(bhi(pv.y), s0.w, h0.w), 0.f)),
                pack2(fmaxf(fmaf(blo(pv.z), s1.x, h1.x), 0.f), fmaxf(fmaf(bhi(pv.z), s1.y, h1.y), 0.f)),
                pack2(fmaxf(fmaf(blo(pv.w), s1.z, h1.z), 0.f), fmaxf(fmaf(bhi(pv.w), s1.w, h1.w), 0.f)));
#pragma unroll
            for (int t = 0; t < NT; ++t) {
                const bf16x8 bf = *(const bf16x8*)&Bp[(((ks * NT + t) * 64) + lane) * 8];
                acc[t] = __builtin_amdgcn_mfma_f32_16x16x32_bf16(aact, bf, acc[t], 0, 0, 0);
            }
#pragma unroll
            for (int t = 0; t < NT; ++t) {
                const bf16x8 bf = *(const bf16x8*)&Bp[((((ks + 4) * NT + t) * 64) + lane) * 8];
                acc[t] = __builtin_amdgcn_mfma_f32_16x16x32_bf16(apre, bf, acc[t], 0, 0, 0);
            }
        }
    }

    float* cl = Cl[w];
#pragma unroll
    for (int t0 = 0; t0 < NT; t0 += TC) {
#pragma unroll
        for (int tt = 0; tt < TC; ++tt)
#pragma unroll
            for (int r = 0; r < 4; ++r)
                cl[(quad * 4 + r) * NCC + tt * 16 + lane15] = acc[t0 + tt][r];
        if (FP8OUT) {
            constexpr int BPL = NCC / 4;
            const int f = lane * BPL;
            const int r = f / NCC;
            const int col = f % NCC;
            const int grow = row0 + w * 16 + r;
            unsigned ou[BPL / 4];
#pragma unroll
            for (int q = 0; q < BPL / 4; ++q) {
                const float4 v = *(const float4*)&cl[f + q * 4];
                ou[q] = pk_fp8x4(v.x, v.y, v.z, v.w);
            }
            if (grow < M) {
                unsigned char* cp = (unsigned char*)Cv + (long)grow * (NT * 16) + t0 * 16 + col;
                if (BPL == 16) *(uint4*)cp = make_uint4(ou[0], ou[1], ou[2], ou[3]);
                else           *(uint2*)cp = make_uint2(ou[0], ou[1]);
            }
        } else {
#pragma unroll
            for (int i = 0; i < (16 * NCC) / 512; ++i) {
                const int f = i * 512 + lane * 8;
                const int r = f / NCC;
                const int col = f % NCC;
                const int grow = row0 + w * 16 + r;
                const float4 lo = *(const float4*)&cl[f];
                const float4 hi = *(const float4*)&cl[f + 4];
                uint4 o;
                o.x = pack2(lo.x, lo.y);
                o.y = pack2(lo.z, lo.w);
                o.z = pack2(hi.x, hi.y);
                o.w = pack2(hi.z, hi.w);
                if (grow < M) *(uint4*)((short*)Cv + (long)grow * (NT * 16) + t0 * 16 + col) = o;
            }
        }
    }
}

// fused: layer-0 GEMM (fp8 C) + phase-1 LDS histogram + W1/W2 packing
__global__ __launch_bounds__(256) void gemm0_hist1(
    const float* __restrict__ x, const short* __restrict__ Bp, unsigned char* __restrict__ C, int M,
    const int* __restrict__ dst, int* __restrict__ bh,
    const float* __restrict__ W1, const float* __restrict__ W2,
    short* __restrict__ Bp1, short* __restrict__ Bp2)
{
    __shared__ int cnt[256];
    if (blockIdx.x < GB0) {
        gemm_body<8, 0, true>(x, Bp, C, M, nullptr, nullptr, nullptr, nullptr);
    } else if (blockIdx.x < GB0 + NBLK1) {
        const int k = blockIdx.x - GB0;
        cnt[threadIdx.x] = 0;
        __syncthreads();
        const int base = k * 2048;
#pragma unroll
        for (int i = 0; i < 8; ++i) {
            const int e = base + i * 256 + threadIdx.x;
            if (e < NE) atomicAdd(&cnt[(unsigned)dst[e] >> 8], 1);
        }
        __syncthreads();
        bh[k * 256 + threadIdx.x] = cnt[threadIdx.x];
    } else if (blockIdx.x < GB0 + NBLK1 + 128) {
        packb_body(W1, Bp1, 8, blockIdx.x - (GB0 + NBLK1));
    } else {
        packb_body(W2, Bp2, 2, blockIdx.x - (GB0 + NBLK1 + 128));
    }
}

// S1: per-bucket exclusive prefix over the NBLK1 chunk-counts (in place), total -> btot
__global__ __launch_bounds__(256) void s1_k(int* __restrict__ bh, int* __restrict__ btot)
{
    __shared__ int a[512];
    const int b = blockIdx.x;
    const int t = threadIdx.x;
    const int v0 = (t < NBLK1) ? bh[t * 256 + b] : 0;
    const int v1 = (t + 256 < NBLK1) ? bh[(t + 256) * 256 + b] : 0;
    a[t] = v0; a[256 + t] = v1;
    __syncthreads();
    for (int off = 1; off < 256; off <<= 1) {
        const int t0 = (t >= off) ? a[t - off] : 0;
        const int t1 = (t >= off) ? a[256 + t - off] : 0;
        __syncthreads();
        a[t] += t0; a[256 + t] += t1;
        __syncthreads();
    }
    const int half = a[255];
    __syncthreads();
    a[256 + t] += half;
    __syncthreads();
    bh[t * 256 + b] = a[t] - v0;
    if (t + 256 < NBLK1) bh[(t + 256) * 256 + b] = a[256 + t] - v1;
    if (t == 255) btot[b] = a[511];
}

// scatter1: partition into bucket-contiguous staging; base computed by LDS scan of btot
__global__ __launch_bounds__(256) void scatter1_k(
    const int* __restrict__ src, const int* __restrict__ dst, const float* __restrict__ ew,
    const int* __restrict__ bh, const int* __restrict__ btot,
    unsigned* __restrict__ ebA, unsigned char* __restrict__ ebB)
{
    __shared__ int tmp[256];
    __shared__ int myoff[256];
    const int k = blockIdx.x;
    const int t = threadIdx.x;
    const int v = (t < NBUCK) ? btot[t] : 0;
    tmp[t] = v;
    __syncthreads();
    for (int off = 1; off < 256; off <<= 1) {
        const int x = (t >= off) ? tmp[t - off] : 0;
        __syncthreads();
        tmp[t] += x;
        __syncthreads();
    }
    myoff[t] = bh[k * 256 + t] + (tmp[t] - v);
    __syncthreads();
    const int ebase = k * 2048;
#pragma unroll
    for (int i = 0; i < 8; ++i) {
        const int e = ebase + i * 256 + t;
        if (e < NE) {
            const int d = dst[e];
            const int pos = atomicAdd(&myoff[(unsigned)d >> 8], 1);
            const unsigned wb = (unsigned)__half_as_ushort(__float2half_rn(ew[e]));
            ebA[pos] = ((unsigned)src[e] & 0xFFFFu) | (wb << 16);
            ebB[pos] = (unsigned char)(d & 255);
        }
    }
}

// phase2: per bucket: count -> scan -> rs + final pe scatter (LDS only)
__global__ __launch_bounds__(256) void phase2_k(
    const unsigned* __restrict__ ebA, const unsigned char* __restrict__ ebB,
    const int* __restrict__ btot, int* __restrict__ rs, unsigned* __restrict__ pe)
{
    __shared__ int bscan[256];
    __shared__ int cnt[256];
    __shared__ int cur[256];
    const int b = blockIdx.x;
    const int t = threadIdx.x;
    const int v0 = (t < NBUCK) ? btot[t] : 0;
    bscan[t] = v0;
    __syncthreads();
    for (int off = 1; off < 256; off <<= 1) {
        const int x = (t >= off) ? bscan[t - off] : 0;
        __syncthreads();
        bscan[t] += x;
        __syncthreads();
    }
    const int e1 = bscan[b];
    const int e0 = e1 - btot[b];
    cnt[t] = 0;
    __syncthreads();
    for (int e = e0 + t; e < e1; e += 256) atomicAdd(&cnt[ebB[e]], 1);
    __syncthreads();
    const int v = cnt[t];
    __syncthreads();
    for (int off = 1; off < 256; off <<= 1) {
        const int x = (t >= off) ? cnt[t - off] : 0;
        __syncthreads();
        cnt[t] += x;
        __syncthreads();
    }
    const int exc = cnt[t] - v;
    const int node = b * 256 + t;
    if (node < NN) rs[node] = e0 + exc;
    if (b == 0 && t == 0) rs[NN] = NE;
    cur[t] = e0 + exc;
    __syncthreads();
    for (int e = e0 + t; e < e1; e += 256) {
        const int pos = atomicAdd(&cur[ebB[e]], 1);
        pe[pos] = ebA[e];
    }
}

template <int NT>
__global__ __launch_bounds__(256) void gemm_bn(
    const unsigned* __restrict__ A, const short* __restrict__ Bp, short* __restrict__ C, int M,
    const float* __restrict__ sum, const float* __restrict__ ss,
    const float* __restrict__ gam, const float* __restrict__ bet)
{
    gemm_body<NT, 1, false>(A, Bp, C, M, sum, ss, gam, bet);
}

// ===== layer-0 aggregation, fp8 h, XCD-sharded quarters =====
// q = blockIdx&3 (XCDs {q,q+4}); 8 lanes/node, 1 uint (4 fp8 ch) per lane
__global__ __launch_bounds__(256) void agg128f8(
    const unsigned* __restrict__ h4, const int* __restrict__ rs,
    const unsigned* __restrict__ pe, unsigned* __restrict__ outp)
{
    const int q = blockIdx.x & 3;
    const int node = (blockIdx.x >> 2) * 32 + (threadIdx.x >> 3);
    if (node >= NN) return;
    const int l = threadIdx.x & 7;
    const unsigned* hq = h4 + q * 8 + l;
    int j = rs[node];
    const int j1 = rs[node + 1];
    float a0[4], a1[4], a2[4], a3[4];
#pragma unroll
    for (int t = 0; t < 4; ++t) { a0[t] = 0.f; a1[t] = 0.f; a2[t] = 0.f; a3[t] = 0.f; }
    for (; j + 7 < j1; j += 8) {
        unsigned u[8], v[8];
#pragma unroll
        for (int t = 0; t < 8; ++t) u[t] = pe[j + t];
#pragma unroll
        for (int t = 0; t < 8; ++t) v[t] = hq[(long)(u[t] & 0xFFFFu) * 32];
#pragma unroll
        for (int t = 0; t < 8; ++t) {
            const float w = edgew(u[t]);
            const f32x2 lo = __builtin_amdgcn_cvt_pk_f32_fp8((int)v[t], false);
            const f32x2 hi = __builtin_amdgcn_cvt_pk_f32_fp8((int)v[t], true);
            a0[t & 3] = fmaf(w, lo.x, a0[t & 3]);
            a1[t & 3] = fmaf(w, lo.y, a1[t & 3]);
            a2[t & 3] = fmaf(w, hi.x, a2[t & 3]);
            a3[t & 3] = fmaf(w, hi.y, a3[t & 3]);
        }
    }
    for (; j < j1; ++j) {
        const unsigned u = pe[j];
        const unsigned v = hq[(long)(u & 0xFFFFu) * 32];
        const float w = edgew(u);
        const f32x2 lo = __builtin_amdgcn_cvt_pk_f32_fp8((int)v, false);
        const f32x2 hi = __builtin_amdgcn_cvt_pk_f32_fp8((int)v, true);
        a0[0] = fmaf(w, lo.x, a0[0]);
        a1[0] = fmaf(w, lo.y, a1[0]);
        a2[0] = fmaf(w, hi.x, a2[0]);
        a3[0] = fmaf(w, hi.y, a3[0]);
    }
    uint2 o;
    o.x = pack2((a0[0] + a0[1]) + (a0[2] + a0[3]), (a1[0] + a1[1]) + (a1[2] + a1[3]));
    o.y = pack2((a2[0] + a2[1]) + (a2[2] + a2[3]), (a3[0] + a3[1]) + (a3[2] + a3[3]));
    ((uint2*)outp)[(long)node * 32 + q * 8 + l] = o;
}

// ===== layer-1 aggregation, bf16 h, XCD-sharded eighths =====
// q = blockIdx&7 (one XCD per eighth); 8 lanes/node, 1 uint (2 bf16 ch) per lane
__global__ __launch_bounds__(256) void agg128b(
    const unsigned* __restrict__ h2, const int* __restrict__ rs,
    const unsigned* __restrict__ pe, unsigned* __restrict__ outp)
{
    const int q = blockIdx.x & 7;
    const int node = (blockIdx.x >> 3) * 32 + (threadIdx.x >> 3);
    if (node >= NN) return;
    const int l = threadIdx.x & 7;
    const unsigned* hq = h2 + q * 8 + l;
    int j = rs[node];
    const int j1 = rs[node + 1];
    float a0[4], a1[4];
#pragma unroll
    for (int t = 0; t < 4; ++t) { a0[t] = 0.f; a1[t] = 0.f; }
    for (; j + 7 < j1; j += 8) {
        unsigned u[8], v[8];
#pragma unroll
        for (int t = 0; t < 8; ++t) u[t] = pe[j + t];
#pragma unroll
        for (int t = 0; t < 8; ++t) v[t] = hq[(long)(u[t] & 0xFFFFu) * 64];
#pragma unroll
        for (int t = 0; t < 8; ++t) {
            const float w = edgew(u[t]);
            a0[t & 3] = fmaf(w, blo(v[t]), a0[t & 3]);
            a1[t & 3] = fmaf(w, bhi(v[t]), a1[t & 3]);
        }
    }
    for (; j < j1; ++j) {
        const unsigned u = pe[j];
        const unsigned v = hq[(long)(u & 0xFFFFu) * 64];
        const float w = edgew(u);
        a0[0] = fmaf(w, blo(v), a0[0]);
        a1[0] = fmaf(w, bhi(v), a1[0]);
    }
    outp[(long)node * 64 + q * 8 + l] =
        pack2((a0[0] + a0[1]) + (a0[2] + a0[3]), (a1[0] + a1[1]) + (a1[2] + a1[3]));
}

// ===== output aggregation, bf16 h rows of 16 uints, XCD-sharded quarters =====
// q = blockIdx&3; 4 lanes/node, 1 uint (2 ch) per lane; fp32 float2 out
__global__ __launch_bounds__(256) void agg32b(
    const unsigned* __restrict__ h2, const int* __restrict__ rs,
    const unsigned* __restrict__ pe, float* __restrict__ out)
{
    const int q = blockIdx.x & 3;
    const int node = (blockIdx.x >> 2) * 64 + (threadIdx.x >> 2);
    if (node >= NN) return;
    const int l = threadIdx.x & 3;
    const unsigned* hq = h2 + q * 4 + l;
    int j = rs[node];
    const int j1 = rs[node + 1];
    float a0[4], a1[4];
#pragma unroll
    for (int t = 0; t < 4; ++t) { a0[t] = 0.f; a1[t] = 0.f; }
    for (; j + 7 < j1; j += 8) {
        unsigned u[8], v[8];
#pragma unroll
        for (int t = 0; t < 8; ++t) u[t] = pe[j + t];
#pragma unroll
        for (int t = 0; t < 8; ++t) v[t] = hq[(long)(u[t] & 0xFFFFu) * 16];
#pragma unroll
        for (int t = 0; t < 8; ++t) {
            const float w = edgew(u[t]);
            a0[t & 3] = fmaf(w, blo(v[t]), a0[t & 3]);
            a1[t & 3] = fmaf(w, bhi(v[t]), a1[t & 3]);
        }
    }
    for (; j < j1; ++j) {
        const unsigned u = pe[j];
        const unsigned v = hq[(long)(u & 0xFFFFu) * 16];
        const float w = edgew(u);
        a0[0] = fmaf(w, blo(v), a0[0]);
        a1[0] = fmaf(w, bhi(v), a1[0]);
    }
    float2 o;
    o.x = (a0[0] + a0[1]) + (a0[2] + a0[3]);
    o.y = (a1[0] + a1[1]) + (a1[2] + a1[3]);
    *(float2*)&out[(long)node * 32 + q * 8 + l * 2] = o;
}

// ================= BN stats (pre rows = 64 uints bf16x2), row-pair unrolled =================
__global__ __launch_bounds__(256) void bn_stats_b(
    const unsigned* __restrict__ pre, float* __restrict__ sum, float* __restrict__ ss, int M)
{
    const int c2 = threadIdx.x & 63;
    const int g = threadIdx.x >> 6;
    float s0 = 0.f, s1 = 0.f, q0 = 0.f, q1 = 0.f;
    float s2 = 0.f, s3 = 0.f, q2 = 0.f, q3 = 0.f;
    for (int row = blockIdx.x * 8 + g * 2; row < M; row += gridDim.x * 8) {
        const unsigned v = pre[(long)row * 64 + c2];
        const unsigned v2 = pre[(long)(row + 1) * 64 + c2];
        const float lo = blo(v), hi = bhi(v);
        const float lo2 = blo(v2), hi2 = bhi(v2);
        s0 += lo; s1 += hi;
        q0 = fmaf(lo, lo, q0); q1 = fmaf(hi, hi, q1);
        s2 += lo2; s3 += hi2;
        q2 = fmaf(lo2, lo2, q2); q3 = fmaf(hi2, hi2, q3);
    }
    s0 += s2; s1 += s3; q0 += q2; q1 += q3;
    __shared__ float A0[256], A1[256], B0[256], B1[256];
    A0[threadIdx.x] = s0; A1[threadIdx.x] = s1;
    B0[threadIdx.x] = q0; B1[threadIdx.x] = q1;
    __syncthreads();
    if (threadIdx.x < 64) {
        const int t = threadIdx.x;
        atomicAdd(&sum[2 * t],     A0[t] + A0[t + 64] + A0[t + 128] + A0[t + 192]);
        atomicAdd(&sum[2 * t + 1], A1[t] + A1[t + 64] + A1[t + 128] + A1[t + 192]);
        atomicAdd(&ss[2 * t],      B0[t] + B0[t + 64] + B0[t + 128] + B0[t + 192]);
        atomicAdd(&ss[2 * t + 1],  B1[t] + B1[t + 64] + B1[t + 128] + B1[t + 192]);
    }
}

extern "C" void kernel_launch(void* const* d_in, const int* in_sizes, int n_in,
                              void* d_out, int out_size, void* d_ws, size_t ws_size,
                              hipStream_t stream) {
    const float* x   = (const float*)d_in[0];
    const int*   src = (const int*)d_in[1];
    const int*   dst = (const int*)d_in[2];
    const float* ew  = (const float*)d_in[3];
    const float* W0  = (const float*)d_in[4];
    const float* W1  = (const float*)d_in[5];
    const float* W2  = (const float*)d_in[6];
    const float* g0  = (const float*)d_in[7];
    const float* b0  = (const float*)d_in[8];
    const float* g1  = (const float*)d_in[9];
    const float* b1  = (const float*)d_in[10];
    float* out = (float*)d_out;

    // workspace layout (h sized for bf16 [NN,128]; fp8 layer-0 aliases the front)
    short* h   = (short*)d_ws;                         // bf16 [NN*128] / fp8 [NN*128] bytes
    unsigned* x1p = (unsigned*)(h + (size_t)NN * 128); // [NN*64] uints = pre-only bf16x2
    float* st  = (float*)(x1p + (size_t)NN * 64);      // 1024 floats
    int*  rs   = (int*)(st + 1024);                    // 50004
    int*  bh   = rs + 50004;                           // NBLK1*256
    int*  btot = bh + NBLK1 * 256;                     // 256
    unsigned* ebA = (unsigned*)(btot + 256);           // NE staged src|w
    unsigned char* ebB = (unsigned char*)(ebA + NE);   // NE dst low bytes
    unsigned* pe = (unsigned*)(ebB + ((NE + 255) & ~255)); // NE final packed edges
    short* Bp0 = (short*)(pe + NE);                    // 32768
    short* Bp1 = Bp0 + 32768;                          // 32768
    short* Bp2 = Bp1 + 32768;                          // 8192

    float* sum0 = st,       *ss0 = st + 128;
    float* sum1 = st + 512, *ss1 = st + 640;

    hipMemsetAsync(st, 0, 1024 * 4, stream);

    packb0_k<<<128, 256, 0, stream>>>(W0, Bp0);

    // layer-0 GEMM (fp8 h) + phase-1 histogram + W1/W2 packing (one launch)
    gemm0_hist1<<<GB0 + NBLK1 + 160, 256, 0, stream>>>(x, Bp0, (unsigned char*)h, NN, dst, bh, W1, W2, Bp1, Bp2);

    s1_k<<<NBUCK, 256, 0, stream>>>(bh, btot);
    scatter1_k<<<NBLK1, 256, 0, stream>>>(src, dst, ew, bh, btot, ebA, ebB);
    phase2_k<<<NBUCK, 256, 0, stream>>>(ebA, ebB, btot, rs, pe);

    // ---- layer 0 aggregation (fp8, quarter-sharded) + stats ----
    agg128f8<<<4 * 1563, 256, 0, stream>>>((const unsigned*)h, rs, pe, x1p);
    bn_stats_b<<<782, 256, 0, stream>>>(x1p, sum0, ss0, NN);

    // ---- layer 1 (BN0+ReLU fused into fragment load; bf16 h out) ----
    gemm_bn<8><<<782, 256, 0, stream>>>(x1p, Bp1, h, NN, sum0, ss0, g0, b0);
    agg128b<<<8 * 1563, 256, 0, stream>>>((const unsigned*)h, rs, pe, x1p);
    bn_stats_b<<<782, 256, 0, stream>>>(x1p, sum1, ss1, NN);

    // ---- output layer (bf16 h out) ----
    gemm_bn<2><<<782, 256, 0, stream>>>(x1p, Bp2, h, NN, sum1, ss1, g1, b1);
    agg32b<<<4 * 782, 256, 0, stream>>>((const unsigned*)h, rs, pe, out);
}